// Round 13
// baseline (3400.977 us; speedup 1.0000x reference)
//
#include <hip/hip_runtime.h>
#include <math.h>

#define NTS 12
#define NND 2048
#define NED 32768
#define XDI 128
#define HDI 256
#define ZDI 32
#define EPSC 1e-10f
#define NH ((size_t)NND * HDI)        // 524288
#define NZ ((size_t)NND * ZDI)        // 65536
#define ZPL ((size_t)NND * 64)        // 131072
#define XSZ ((size_t)NTS * NND * XDI) // 3145728
#define LSTR 264
#define LPH (16 * 264)
#define DECF 171                      // dec tiles per filler stage

typedef unsigned short u16;
typedef __bf16 bf16x8 __attribute__((ext_vector_type(8)));
typedef float f32x4 __attribute__((ext_vector_type(4)));

#define MF(a, b, c) __builtin_amdgcn_mfma_f32_16x16x32_bf16(a, b, c, 0, 0, 0)

// ---------------- helpers ----------------

__device__ __forceinline__ float lsigf(float x) {
    return fminf(x, 0.f) - log1pf(expf(-fabsf(x)));
}
__device__ __forceinline__ float splus(float v) {
    return fmaxf(v, 0.f) + log1pf(expf(-fabsf(v)));
}
__device__ __forceinline__ u16 f2b(float f) {
    unsigned u = __float_as_uint(f);
    u += 0x7fffu + ((u >> 16) & 1u);
    return (u16)(u >> 16);
}
__device__ __forceinline__ float b2f(u16 b) {
    return __uint_as_float((unsigned)b << 16);
}
__device__ __forceinline__ void f2b2(float v, u16& hi, u16& lo) {
    hi = f2b(v);
    lo = f2b(v - b2f(hi));
}
__device__ __forceinline__ void st_b16(u16* buf, size_t plane, size_t idx, float v) {
    u16 hi, lo;
    f2b2(v, hi, lo);
    buf[idx] = hi;
    buf[plane + idx] = lo;
}
__device__ __forceinline__ void st_b16v4(u16* buf, size_t plane, size_t idx, float4 v) {
    ushort4 h, l;
    f2b2(v.x, h.x, l.x); f2b2(v.y, h.y, l.y);
    f2b2(v.z, h.z, l.z); f2b2(v.w, h.w, l.w);
    *(ushort4*)(buf + idx) = h;
    *(ushort4*)(buf + plane + idx) = l;
}
__device__ __forceinline__ float4 ld_hl4(const u16* b, size_t plane, size_t idx) {
    ushort4 h = *(const ushort4*)(b + idx);
    ushort4 l = *(const ushort4*)(b + plane + idx);
    float4 r;
    r.x = b2f(h.x) + b2f(l.x); r.y = b2f(h.y) + b2f(l.y);
    r.z = b2f(h.z) + b2f(l.z); r.w = b2f(h.w) + b2f(l.w);
    return r;
}
// gather (GIN) of one 256-wide hi/lo row set — 4-way unrolled
__device__ float4 gin_hl(const u16* buf, size_t plane, int n, const int* __restrict__ offs,
                         const int* __restrict__ cs, int lane) {
    int e0 = offs[n], e1 = offs[n + 1];
    size_t c4 = (size_t)lane * 4;
    float4 a0 = ld_hl4(buf, plane, (size_t)n * HDI + c4);
    float4 a1 = {0.f, 0.f, 0.f, 0.f}, a2 = {0.f, 0.f, 0.f, 0.f}, a3 = {0.f, 0.f, 0.f, 0.f};
    int j = e0;
    for (; j + 3 < e1; j += 4) {
        int s0 = cs[j], s1 = cs[j + 1], s2 = cs[j + 2], s3 = cs[j + 3];
        float4 v0 = ld_hl4(buf, plane, (size_t)s0 * HDI + c4);
        float4 v1 = ld_hl4(buf, plane, (size_t)s1 * HDI + c4);
        float4 v2 = ld_hl4(buf, plane, (size_t)s2 * HDI + c4);
        float4 v3 = ld_hl4(buf, plane, (size_t)s3 * HDI + c4);
        a0.x += v0.x; a0.y += v0.y; a0.z += v0.z; a0.w += v0.w;
        a1.x += v1.x; a1.y += v1.y; a1.z += v1.z; a1.w += v1.w;
        a2.x += v2.x; a2.y += v2.y; a2.z += v2.z; a2.w += v2.w;
        a3.x += v3.x; a3.y += v3.y; a3.z += v3.z; a3.w += v3.w;
    }
    for (; j < e1; ++j) {
        float4 v = ld_hl4(buf, plane, (size_t)cs[j] * HDI + c4);
        a0.x += v.x; a0.y += v.y; a0.z += v.z; a0.w += v.w;
    }
    a0.x += a1.x + a2.x + a3.x;
    a0.y += a1.y + a2.y + a3.y;
    a0.z += a1.z + a2.z + a3.z;
    a0.w += a1.w + a2.w + a3.w;
    return a0;
}

// wt arena offsets (elems): m0 K=128, m1 K=64, else K=256; each = 2*K*256 elems
__host__ __device__ inline size_t wtoff(int m) {
    if (m == 0) return 0;
    if (m == 1) return 65536;
    return 98304 + (size_t)(m - 2) * 131072;
}

// split-bf16 64x16 wave GEMM pass: 12 accumulators (4 row-subtiles x 3-split)
__device__ __forceinline__ void mm64(f32x4* A12, const u16* __restrict__ Ahi, size_t apl,
                                     const u16* __restrict__ Bt, int K,
                                     int row0, int cc, int lr, int kg) {
    const u16* bp = Bt + (size_t)(cc * 16 + lr) * K + kg;
    const u16* blp = bp + (size_t)K * HDI;
    const u16* ap0 = Ahi + (size_t)(row0 + lr) * K + kg;
    for (int k0 = 0; k0 < K; k0 += 32) {
        bf16x8 bh = *(const bf16x8*)(bp + k0);
        bf16x8 bl = *(const bf16x8*)(blp + k0);
#pragma unroll
        for (int s = 0; s < 4; s++) {
            const u16* ap = ap0 + (size_t)(16 * s) * K;
            bf16x8 ah = *(const bf16x8*)(ap + k0);
            bf16x8 al = *(const bf16x8*)(ap + apl + k0);
            A12[s * 3 + 0] = MF(ah, bh, A12[s * 3 + 0]);
            A12[s * 3 + 1] = MF(al, bh, A12[s * 3 + 1]);
            A12[s * 3 + 2] = MF(ah, bl, A12[s * 3 + 2]);
        }
    }
}
// LDS-A (16 rows) x 4 col-tiles
__device__ __forceinline__ void mml16(f32x4* a12, const u16* lds,
                                      const u16* __restrict__ Bt, int K,
                                      int ctbase, int lr, int kg) {
    for (int k0 = 0; k0 < K; k0 += 32) {
        bf16x8 ah = *(const bf16x8*)(lds + lr * LSTR + kg + k0);
        bf16x8 al = *(const bf16x8*)(lds + LPH + lr * LSTR + kg + k0);
#pragma unroll
        for (int ct = 0; ct < 4; ct++) {
            const u16* bp = Bt + (size_t)((ctbase + ct) * 16 + lr) * K + kg + k0;
            bf16x8 bh = *(const bf16x8*)bp;
            bf16x8 bl = *(const bf16x8*)(bp + (size_t)K * HDI);
            a12[ct * 3 + 0] = MF(ah, bh, a12[ct * 3 + 0]);
            a12[ct * 3 + 1] = MF(al, bh, a12[ct * 3 + 1]);
            a12[ct * 3 + 2] = MF(ah, bl, a12[ct * 3 + 2]);
        }
    }
}

__device__ __forceinline__ void epi_hl(f32x4* A12, u16* dst, size_t plane,
                                       int row0, int cc, int lane, int relu) {
    int col = cc * 16 + (lane & 15);
    int rb0 = (lane >> 4) << 2;
#pragma unroll
    for (int s = 0; s < 4; s++)
#pragma unroll
        for (int i = 0; i < 4; i++) {
            int row = row0 + s * 16 + rb0 + i;
            float v = A12[s * 3][i] + A12[s * 3 + 1][i] + A12[s * 3 + 2][i];
            if (relu) v = fmaxf(v, 0.f);
            st_b16(dst, plane, (size_t)row * HDI + col, v);
        }
}

// ---------------- dec tile (64x64 of z_s@z_d^T + store + BCE partials) ----------------
__device__ void dec_tile(const float* __restrict__ zcatf, const float* __restrict__ adjt,
                         float* __restrict__ dect, double* __restrict__ bcet,
                         int db, int tid, float* smf) {
    float (*zsS)[68] = (float(*)[68])smf;
    float (*zdS)[68] = (float(*)[68])(smf + 32 * 68);
    const int tx = tid & 15, ty = tid >> 4;
    const int c0 = (db & 31) * 64, r0 = (db >> 5) * 64;
    const int lrow = tid >> 2;
    const int lk = (tid & 3) * 8;
    float4 v0 = *(const float4*)&zcatf[(size_t)(r0 + lrow) * 64 + lk];
    float4 v1 = *(const float4*)&zcatf[(size_t)(r0 + lrow) * 64 + lk + 4];
    float4 w0 = *(const float4*)&zcatf[(size_t)(c0 + lrow) * 64 + 32 + lk];
    float4 w1 = *(const float4*)&zcatf[(size_t)(c0 + lrow) * 64 + 32 + lk + 4];
    zsS[lk + 0][lrow] = v0.x; zsS[lk + 1][lrow] = v0.y; zsS[lk + 2][lrow] = v0.z; zsS[lk + 3][lrow] = v0.w;
    zsS[lk + 4][lrow] = v1.x; zsS[lk + 5][lrow] = v1.y; zsS[lk + 6][lrow] = v1.z; zsS[lk + 7][lrow] = v1.w;
    zdS[lk + 0][lrow] = w0.x; zdS[lk + 1][lrow] = w0.y; zdS[lk + 2][lrow] = w0.z; zdS[lk + 3][lrow] = w0.w;
    zdS[lk + 4][lrow] = w1.x; zdS[lk + 5][lrow] = w1.y; zdS[lk + 6][lrow] = w1.z; zdS[lk + 7][lrow] = w1.w;
    __syncthreads();

    float acc[4][4] = {};
#pragma unroll
    for (int k = 0; k < 32; k++) {
        const float4 a4 = *(const float4*)&zsS[k][ty * 4];
        const float4 b4 = *(const float4*)&zdS[k][tx * 4];
        const float aa[4] = {a4.x, a4.y, a4.z, a4.w};
        const float bb[4] = {b4.x, b4.y, b4.z, b4.w};
#pragma unroll
        for (int i = 0; i < 4; i++)
#pragma unroll
            for (int j = 0; j < 4; j++) acc[i][j] += aa[i] * bb[j];
    }

    float pa = 0.f, p1 = 0.f, p2 = 0.f;
#pragma unroll
    for (int i = 0; i < 4; i++) {
        const int r = r0 + ty * 4 + i;
        const float4 av4 = *(const float4*)&adjt[(size_t)r * NND + c0 + tx * 4];
        const float av[4] = {av4.x, av4.y, av4.z, av4.w};
        float* drow = &dect[(size_t)r * NND + c0 + tx * 4];
#pragma unroll
        for (int j = 0; j < 4; j++) {
            float d = acc[i][j];
            __builtin_nontemporal_store(d, &drow[j]);
            float a = av[j];
            pa += a;
            p1 += a * lsigf(d);
            p2 += (1.f - a) * lsigf(-d);
        }
    }
    __syncthreads();
    smf[tid] = pa; smf[256 + tid] = p1; smf[512 + tid] = p2;
    __syncthreads();
    for (int o = 128; o > 0; o >>= 1) {
        if (tid < o) {
            smf[tid] += smf[tid + o];
            smf[256 + tid] += smf[256 + tid + o];
            smf[512 + tid] += smf[512 + tid + o];
        }
        __syncthreads();
    }
    if (tid == 0) {
        double* b = bcet + (size_t)db * 3;
        b[0] = (double)smf[0];
        b[1] = (double)smf[256];
        b[2] = (double)smf[512];
    }
}

// ---------------- setup kernels ----------------

__global__ __launch_bounds__(256) void k0_setup(const int* __restrict__ ei,
                                                const float* __restrict__ x,
                                                const float* w_phix, const float* w_phiz,
                                                const float* w_enc, const float* w_pri,
                                                const float* w_gx0, const float* w_gx1,
                                                const float* w_gh,
                                                u16* __restrict__ warena, u16* __restrict__ xb,
                                                int* __restrict__ counts) {
    const int bid = blockIdx.x, tid = threadIdx.x;
    if (bid < 1536) {
        int idx = bid * 256 + tid;
        int t = idx >> 15, e = idx & (NED - 1);
        atomicAdd(&counts[t * NND + ei[(size_t)t * 2 * NED + NED + e]], 1);
    } else if (bid < 7424) {
        int u = bid - 1536;
        int m = u >> 8, k = u & 255;
        const int Kt = (m == 0) ? 128 : (m == 1) ? 64 : 256;
        if (k < Kt) {
            const int srcsel[23] = {0, 1, 2, 2, 2, 2, 3, 3, 4, 4, 4, 4,
                                    4, 4, 6, 6, 6, 5, 5, 5, 6, 6, 6};
            const int srcoff[23] = {0, 0, 0, 65536, 131072, 196608, 0, 65536,
                                    0, 65536, 131072, 196608, 262144, 327680,
                                    0, 65536, 131072, 0, 65536, 131072,
                                    196608, 262144, 327680};
            const float* srcs[7] = {w_phix, w_phiz, w_enc, w_pri, w_gx0, w_gx1, w_gh};
            const float* W = srcs[srcsel[m]] + srcoff[m];
            u16* D = warena + wtoff(m);
            float v = W[(size_t)k * 256 + tid];
            u16 hi, lo;
            f2b2(v, hi, lo);
            D[(size_t)tid * Kt + k] = hi;
            D[(size_t)Kt * 256 + (size_t)tid * Kt + k] = lo;
        }
    } else {
        size_t i = (size_t)(bid - 7424) * 256 + tid;
        float4 v = ((const float4*)x)[i];
        ushort4 h, l;
        f2b2(v.x, h.x, l.x); f2b2(v.y, h.y, l.y);
        f2b2(v.z, h.z, l.z); f2b2(v.w, h.w, l.w);
        ((ushort4*)xb)[i] = h;
        ((ushort4*)(xb + XSZ))[i] = l;
    }
}

__global__ __launch_bounds__(256) void k1_scan_phix(const int* __restrict__ counts,
                                                    int* __restrict__ offs,
                                                    float* __restrict__ deg,
                                                    float* __restrict__ dinv,
                                                    const u16* __restrict__ xb,
                                                    const u16* __restrict__ warena,
                                                    u16* __restrict__ phixb) {
    __shared__ int tsum[256];
    const int bid = blockIdx.x, tid = threadIdx.x;
    if (bid < 12) {
        const int* cnt = counts + bid * NND;
        int* off = offs + bid * (NND + 1);
        float* dg = deg + bid * NND;
        float* dv = dinv + bid * NND;
        int base = tid * 8;
        int local[8];
        int s = 0;
        for (int i = 0; i < 8; i++) { local[i] = s; s += cnt[base + i]; }
        tsum[tid] = s;
        __syncthreads();
        for (int o = 1; o < 256; o <<= 1) {
            int v = (tid >= o) ? tsum[tid - o] : 0;
            __syncthreads();
            tsum[tid] += v;
            __syncthreads();
        }
        int excl = tsum[tid] - s;
        for (int i = 0; i < 8; i++) off[base + i] = excl + local[i];
        if (tid == 255) off[NND] = excl + s;
        for (int i = 0; i < 8; i++) {
            float d = (float)cnt[base + i] + 1.0f;
            dg[base + i] = d;
            dv[base + i] = 1.0f / sqrtf(d);
        }
    } else {
        int u = bid - 12;
        int t = u >> 7, tile = u & 127;
        const int wid = tid >> 6, lane = tid & 63;
        const int lr = lane & 15, kg = (lane >> 4) * 8;
        int row0 = (tile >> 4) * 256 + wid * 64, cc = tile & 15;
        f32x4 A12[12] = {};
        mm64(A12, xb + (size_t)t * NND * XDI, XSZ, warena + wtoff(0), XDI, row0, cc, lr, kg);
        epi_hl(A12, phixb + (size_t)t * 2 * NH, NH, row0, cc, lane, 1);
    }
}

__global__ __launch_bounds__(256) void k2_fill(const int* __restrict__ ei,
                                               const int* __restrict__ offs,
                                               int* __restrict__ cursor,
                                               const float* __restrict__ dinv,
                                               int* __restrict__ csrc,
                                               float* __restrict__ csrw) {
    int idx = blockIdx.x * 256 + threadIdx.x;
    int t = idx >> 15, e = idx & (NED - 1);
    const int* src = ei + (size_t)t * 2 * NED;
    const int* dst = src + NED;
    int d = dst[e], s = src[e];
    const int* off_t = offs + t * (NND + 1);
    int pos = off_t[d] + atomicAdd(&cursor[t * NND + d], 1);
    csrc[(size_t)t * NED + pos] = s;
    csrw[(size_t)t * NED + pos] = dinv[t * NND + s] * dinv[t * NND + d];
}

// ---------------- per-step kernels ----------------

// kA: U_s/U_d GEMM (hi/lo out) + pri GEMM (fp32 relu out)
__global__ __launch_bounds__(256) void kA(const u16* __restrict__ phxt,
                                          const u16* __restrict__ h1b,
                                          const u16* __restrict__ warena,
                                          u16* __restrict__ Ub, float* __restrict__ prif,
                                          const float* __restrict__ b_pri) {
    const int bid = blockIdx.x, tid = threadIdx.x;
    const int wid = tid >> 6, lane = tid & 63;
    const int lr = lane & 15, kg = (lane >> 4) * 8;
    f32x4 A12[12] = {};
    if (bid < 256) {
        int o = bid >> 7, tile = bid & 127;
        int row0 = (tile >> 4) * 256 + wid * 64, cc = tile & 15;
        mm64(A12, phxt, NH, warena + wtoff(2 + 2 * o), HDI, row0, cc, lr, kg);
        mm64(A12, h1b, NH, warena + wtoff(3 + 2 * o), HDI, row0, cc, lr, kg);
        epi_hl(A12, Ub + (size_t)o * 2 * NH, NH, row0, cc, lane, 0);
    } else {
        int q = bid - 256;
        int o = q >> 7, tile = q & 127;
        int row0 = (tile >> 4) * 256 + wid * 64, cc = tile & 15;
        mm64(A12, h1b, NH, warena + wtoff(6 + o), HDI, row0, cc, lr, kg);
        int col = cc * 16 + lr;
        int rb0 = (lane >> 4) << 2;
        float* C = prif + (size_t)o * NH;
        float bv = b_pri[o * HDI + col];
#pragma unroll
        for (int s = 0; s < 4; s++)
#pragma unroll
            for (int i = 0; i < 4; i++) {
                int row = row0 + s * 16 + rb0 + i;
                float v = A12[s * 3][i] + A12[s * 3 + 1][i] + A12[s * 3 + 2][i] + bv;
                C[(size_t)row * HDI + col] = fmaxf(v, 0.f);
            }
    }
}

// kB: fused enc gather + [256->32] smalls, plus prior smalls
__global__ __launch_bounds__(256) void kB(const u16* __restrict__ Ub,
                                          const float* __restrict__ prif,
                                          const int* __restrict__ offs,
                                          const int* __restrict__ cs,
                                          const float* __restrict__ b_enc,
                                          const float* __restrict__ w_mean,
                                          const float* __restrict__ w_std,
                                          const float* __restrict__ w_pm,
                                          const float* __restrict__ b_pm,
                                          const float* __restrict__ w_ps,
                                          const float* __restrict__ b_ps,
                                          float* __restrict__ xw, float* __restrict__ pmps) {
    __shared__ float rowbuf[4][256];
    const int tid = threadIdx.x;
    const int wid = tid >> 6, lane = tid & 63;
    const int u = blockIdx.x * 4 + wid;
    if (u < 4096) {
        int seg = u >> 11, n = u & 2047;
        float4 a = gin_hl(Ub + (size_t)seg * 2 * NH, NH, n, offs, cs, lane);
        const float* eb = b_enc + seg * HDI + lane * 4;
        a.x = fmaxf(a.x + eb[0], 0.f);
        a.y = fmaxf(a.y + eb[1], 0.f);
        a.z = fmaxf(a.z + eb[2], 0.f);
        a.w = fmaxf(a.w + eb[3], 0.f);
        *(float4*)&rowbuf[wid][lane * 4] = a;
        const float* B = ((lane < 32) ? w_mean : w_std) + seg * 8192;
        int m = lane & 31;
        float acc = 0.f;
        const float* rb = rowbuf[wid];
#pragma unroll 8
        for (int k = 0; k < 256; k++) acc += rb[k] * B[k * 32 + m];
        float* O = xw + ((lane < 32) ? seg : 2 + seg) * NZ;
        O[(size_t)n * ZDI + m] = acc;
    } else {
        int q = u - 4096;
        int s = q >> 10, unit = q & 1023;
        int n = unit * 2 + (lane >> 5);
        int m = lane & 31;
        const float* A = prif + ((s < 2) ? 0 : NH);
        const float* B = (s & 1) ? (w_ps + (s >> 1) * 8192) : (w_pm + (s >> 1) * 8192);
        const float* bi = (s & 1) ? (b_ps + (s >> 1) * 32) : (b_pm + (s >> 1) * 32);
        float acc = bi[m];
        const float* ar = A + (size_t)n * HDI;
#pragma unroll 4
        for (int k = 0; k < 256; k += 4) {
            float4 a4 = *(const float4*)(ar + k);
            acc += a4.x * B[(k + 0) * 32 + m];
            acc += a4.y * B[(k + 1) * 32 + m];
            acc += a4.z * B[(k + 2) * 32 + m];
            acc += a4.w * B[(k + 3) * 32 + m];
        }
        if (s & 1) acc = splus(acc);
        pmps[(size_t)s * NZ + (size_t)n * ZDI + m] = acc;
    }
}

// kC: fused gcn(mean)+gin(std)+z+KLD + phi_z (fp32 VALU, K=64) -> phizb hi/lo
__global__ __launch_bounds__(256) void kC(const float* __restrict__ xw,
                                          const float* __restrict__ pmps,
                                          const int* __restrict__ offs,
                                          const int* __restrict__ cs,
                                          const float* __restrict__ cw,
                                          const float* __restrict__ dgv,
                                          const float* __restrict__ b_mean,
                                          const float* __restrict__ b_std,
                                          const float* __restrict__ es,
                                          const float* __restrict__ ed,
                                          const float* __restrict__ w_phiz,
                                          float* __restrict__ zcatf,
                                          u16* __restrict__ phizb,
                                          double* __restrict__ accd) {
    __shared__ float zrow[4][64];
    __shared__ double smd[4];
    const int tid = threadIdx.x;
    const int wid = tid >> 6, lane = tid & 63;
    const int n = blockIdx.x * 4 + wid;
    const int sel = lane >> 5, m = lane & 31;
    const float* xwm = xw + (size_t)sel * NZ;
    const float* xws = xw + (size_t)(2 + sel) * NZ;
    int e0 = offs[n], e1 = offs[n + 1];
    float am0 = 0.f, am1 = 0.f, am2 = 0.f, am3 = 0.f;
    float as0 = xws[(size_t)n * ZDI + m], as1 = 0.f, as2 = 0.f, as3 = 0.f;
    int j = e0;
    for (; j + 3 < e1; j += 4) {
        int s0 = cs[j], s1 = cs[j + 1], s2 = cs[j + 2], s3 = cs[j + 3];
        am0 += cw[j] * xwm[(size_t)s0 * ZDI + m];
        am1 += cw[j + 1] * xwm[(size_t)s1 * ZDI + m];
        am2 += cw[j + 2] * xwm[(size_t)s2 * ZDI + m];
        am3 += cw[j + 3] * xwm[(size_t)s3 * ZDI + m];
        as0 += xws[(size_t)s0 * ZDI + m];
        as1 += xws[(size_t)s1 * ZDI + m];
        as2 += xws[(size_t)s2 * ZDI + m];
        as3 += xws[(size_t)s3 * ZDI + m];
    }
    for (; j < e1; ++j) {
        int s = cs[j];
        am0 += cw[j] * xwm[(size_t)s * ZDI + m];
        as0 += xws[(size_t)s * ZDI + m];
    }
    float am = am0 + am1 + am2 + am3;
    float as_ = as0 + as1 + as2 + as3;
    float mean = am + xwm[(size_t)n * ZDI + m] / dgv[n] + b_mean[sel * 32 + m];
    float sd = splus(as_ + b_std[sel * 32 + m]);
    const float* eps = sel ? ed : es;
    float z = mean + sd * eps[(size_t)n * ZDI + m];
    size_t zi = (size_t)n * 64 + sel * 32 + m;
    zcatf[zi] = z;
    zrow[wid][sel * 32 + m] = z;
    float pm = pmps[(size_t)(sel * 2) * NZ + (size_t)n * ZDI + m];
    float ps = pmps[(size_t)(sel * 2 + 1) * NZ + (size_t)n * ZDI + m];
    float a1v = sd + EPSC, a2v = ps + EPSC;
    float dm = mean - pm;
    double kl = (double)(2.f * (logf(a2v) - logf(a1v)) +
                         (a1v * a1v + dm * dm) / (a2v * a2v) - 1.f);
    // phi_z for this row (same wave wrote zrow[wid]) — fp32, K=64
    {
        const float* zr = zrow[wid];
        const int cbase = lane * 4;
        float a0 = 0.f, a1 = 0.f, a2 = 0.f, a3 = 0.f;
#pragma unroll 4
        for (int k = 0; k < 64; k++) {
            float zv = zr[k];
            const float* wr = w_phiz + k * 256 + cbase;
            a0 += zv * wr[0]; a1 += zv * wr[1]; a2 += zv * wr[2]; a3 += zv * wr[3];
        }
        float4 r;
        r.x = fmaxf(a0, 0.f); r.y = fmaxf(a1, 0.f);
        r.z = fmaxf(a2, 0.f); r.w = fmaxf(a3, 0.f);
        st_b16v4(phizb, NH, (size_t)n * HDI + cbase, r);
    }
#pragma unroll
    for (int o = 32; o > 0; o >>= 1) kl += __shfl_down(kl, o);
    if (lane == 0) smd[wid] = kl;
    __syncthreads();
    if (tid == 0) atomicAdd(accd, smd[0] + smd[1] + smd[2] + smd[3]);
}

// kE: GRU layer0 gate GEMMs (384 main) + dec filler
__global__ __launch_bounds__(256) void kE(const u16* __restrict__ phxt,
                                          const u16* __restrict__ phizb,
                                          const u16* __restrict__ h0b,
                                          const u16* __restrict__ warena,
                                          u16* __restrict__ Pb,
                                          const float* __restrict__ zcatf,
                                          const float* __restrict__ adjt,
                                          float* __restrict__ dect,
                                          double* __restrict__ bcet,
                                          int nmain, int decbase) {
    __shared__ __align__(16) float smf[2 * 32 * 68];
    const int bid = blockIdx.x, tid = threadIdx.x;
    if (bid >= nmain) {
        dec_tile(zcatf, adjt, dect, bcet, decbase + bid - nmain, tid, smf);
        return;
    }
    const int wid = tid >> 6, lane = tid & 63;
    const int lr = lane & 15, kg = (lane >> 4) * 8;
    int o = bid >> 7, tile = bid & 127;
    int row0 = (tile >> 4) * 256 + wid * 64, cc = tile & 15;
    f32x4 A12[12] = {};
    if (o == 0) {
        mm64(A12, phxt, NH, warena + wtoff(8), HDI, row0, cc, lr, kg);
        mm64(A12, phizb, NH, warena + wtoff(9), HDI, row0, cc, lr, kg);
        mm64(A12, h0b, NH, warena + wtoff(14), HDI, row0, cc, lr, kg);
    } else if (o == 1) {
        mm64(A12, phxt, NH, warena + wtoff(10), HDI, row0, cc, lr, kg);
        mm64(A12, phizb, NH, warena + wtoff(11), HDI, row0, cc, lr, kg);
        mm64(A12, h0b, NH, warena + wtoff(15), HDI, row0, cc, lr, kg);
    } else {
        mm64(A12, phxt, NH, warena + wtoff(12), HDI, row0, cc, lr, kg);
        mm64(A12, phizb, NH, warena + wtoff(13), HDI, row0, cc, lr, kg);
    }
    epi_hl(A12, Pb + (size_t)o * 2 * NH, NH, row0, cc, lane, 0);
}

// kE1: GRU layer1 gate GEMMs (384 main) + dec filler
__global__ __launch_bounds__(256) void kE1(const u16* __restrict__ nh0b,
                                           const u16* __restrict__ h1b,
                                           const u16* __restrict__ warena,
                                           u16* __restrict__ Pb,
                                           const float* __restrict__ zcatf,
                                           const float* __restrict__ adjt,
                                           float* __restrict__ dect,
                                           double* __restrict__ bcet,
                                           int nmain, int decbase) {
    __shared__ __align__(16) float smf[2 * 32 * 68];
    const int bid = blockIdx.x, tid = threadIdx.x;
    if (bid >= nmain) {
        dec_tile(zcatf, adjt, dect, bcet, decbase + bid - nmain, tid, smf);
        return;
    }
    const int wid = tid >> 6, lane = tid & 63;
    const int lr = lane & 15, kg = (lane >> 4) * 8;
    int o = bid >> 7, tile = bid & 127;
    int row0 = (tile >> 4) * 256 + wid * 64, cc = tile & 15;
    f32x4 A12[12] = {};
    if (o == 0) {
        mm64(A12, nh0b, NH, warena + wtoff(17), HDI, row0, cc, lr, kg);
        mm64(A12, h1b, NH, warena + wtoff(20), HDI, row0, cc, lr, kg);
    } else if (o == 1) {
        mm64(A12, nh0b, NH, warena + wtoff(18), HDI, row0, cc, lr, kg);
        mm64(A12, h1b, NH, warena + wtoff(21), HDI, row0, cc, lr, kg);
    } else {
        mm64(A12, nh0b, NH, warena + wtoff(19), HDI, row0, cc, lr, kg);
    }
    epi_hl(A12, Pb + (size_t)o * 2 * NH, NH, row0, cc, lane, 0);
}

// kFG: fused zG/rh gather + R GEMM (128 main, 16-row tiles) + dec filler
__global__ __launch_bounds__(256) void kFG(const u16* __restrict__ Pb,
                                           const u16* __restrict__ hb,
                                           const u16* __restrict__ warena, int wtm,
                                           float* __restrict__ zGf, u16* __restrict__ Rb,
                                           const int* __restrict__ offs,
                                           const int* __restrict__ cs,
                                           const float* __restrict__ zcatf,
                                           const float* __restrict__ adjt,
                                           float* __restrict__ dect,
                                           double* __restrict__ bcet,
                                           int nmain, int decbase) {
    __shared__ __align__(16) char smem[17408];
    const int bid = blockIdx.x, tid = threadIdx.x;
    if (bid >= nmain) {
        dec_tile(zcatf, adjt, dect, bcet, decbase + bid - nmain, tid, (float*)smem);
        return;
    }
    u16* lrh = (u16*)smem;
    const int wid = tid >> 6, lane = tid & 63;
    const int lr = lane & 15, kg = (lane >> 4) * 8;
    const int n0 = bid * 16;
    const int c4 = lane * 4;
    for (int rr = 0; rr < 4; rr++) {
        int rl = wid * 4 + rr, n = n0 + rl;
        size_t idx = (size_t)n * HDI + c4;
        float4 az = gin_hl(Pb, NH, n, offs, cs, lane);
        float4 zg;
        zg.x = 1.f / (1.f + expf(-az.x)); zg.y = 1.f / (1.f + expf(-az.y));
        zg.z = 1.f / (1.f + expf(-az.z)); zg.w = 1.f / (1.f + expf(-az.w));
        *(float4*)&zGf[idx] = zg;
        float4 ar = gin_hl(Pb + 2 * NH, NH, n, offs, cs, lane);
        float4 h4 = ld_hl4(hb, NH, idx);
        float4 rh;
        rh.x = h4.x / (1.f + expf(-ar.x)); rh.y = h4.y / (1.f + expf(-ar.y));
        rh.z = h4.z / (1.f + expf(-ar.z)); rh.w = h4.w / (1.f + expf(-ar.w));
        ushort4 hh, ll;
        f2b2(rh.x, hh.x, ll.x); f2b2(rh.y, hh.y, ll.y);
        f2b2(rh.z, hh.z, ll.z); f2b2(rh.w, hh.w, ll.w);
        *(ushort4*)(lrh + rl * LSTR + c4) = hh;
        *(ushort4*)(lrh + LPH + rl * LSTR + c4) = ll;
    }
    __syncthreads();
    f32x4 a12[12] = {};
    mml16(a12, lrh, warena + wtoff(wtm), 256, wid * 4, lr, kg);
    const u16* Ph = Pb + 4 * NH;
    int rb0 = (lane >> 4) * 4;
#pragma unroll
    for (int ct = 0; ct < 4; ct++)
#pragma unroll
        for (int i = 0; i < 4; i++) {
            int row = n0 + rb0 + i;
            int col = (wid * 4 + ct) * 16 + lr;
            size_t idx = (size_t)row * HDI + col;
            float v = a12[ct * 3][i] + a12[ct * 3 + 1][i] + a12[ct * 3 + 2][i] +
                      b2f(Ph[idx]) + b2f(Ph[NH + idx]);
            st_b16(Rb, NH, idx, v);
        }
}

// kH: nh = zG*h + (1-zG)*tanh(G(R)) (512 main) + dec filler
__global__ __launch_bounds__(256) void kH(const u16* __restrict__ Rb,
                                          const float* __restrict__ zGf,
                                          const u16* __restrict__ hb,
                                          u16* __restrict__ nhb,
                                          const int* __restrict__ offs,
                                          const int* __restrict__ cs,
                                          const float* __restrict__ zcatf,
                                          const float* __restrict__ adjt,
                                          float* __restrict__ dect,
                                          double* __restrict__ bcet,
                                          int nmain, int decbase, int deccnt) {
    __shared__ __align__(16) float smf[2 * 32 * 68];
    const int bid = blockIdx.x, tid = threadIdx.x;
    if (bid >= nmain) {
        int db = decbase + bid - nmain;
        if (db < 1024) dec_tile(zcatf, adjt, dect, bcet, db, tid, smf);
        return;
    }
    const int wid = tid >> 6, lane = tid & 63;
    const int n = bid * 4 + wid;
    size_t idx = (size_t)n * HDI + lane * 4;
    float4 a = gin_hl(Rb, NH, n, offs, cs, lane);
    float4 z4 = *(const float4*)&zGf[idx];
    float4 h4 = ld_hl4(hb, NH, idx);
    float4 o;
    o.x = z4.x * h4.x + (1.f - z4.x) * tanhf(a.x);
    o.y = z4.y * h4.y + (1.f - z4.y) * tanhf(a.y);
    o.z = z4.z * h4.z + (1.f - z4.z) * tanhf(a.z);
    o.w = z4.w * h4.w + (1.f - z4.w) * tanhf(a.w);
    st_b16v4(nhb, NH, idx, o);
}

// finalize — wave-parallel reductions
__global__ __launch_bounds__(256) void kFin(const double* __restrict__ accd,
                                            const double* __restrict__ bce,
                                            float* __restrict__ out) {
    __shared__ double sums[36];
    const int tid = threadIdx.x;
    const int wid = tid >> 6, lane = tid & 63;
    for (int p = wid; p < 36; p += 4) {
        int t = p / 3, c = p % 3;
        double s = 0.0;
        for (int i = lane; i < 1024; i += 64) s += bce[((size_t)t * 1024 + i) * 3 + c];
#pragma unroll
        for (int o = 32; o > 0; o >>= 1) s += __shfl_down(s, o);
        if (lane == 0) sums[p] = s;
    }
    __syncthreads();
    if (tid == 0) {
        const double nn2 = (double)NND * (double)NND;
        out[0] = (float)(0.5 * accd[0] / nn2);
        double nll = 0.0;
        for (int t = 0; t < NTS; ++t) {
            double s = sums[t * 3 + 0];
            double S1 = sums[t * 3 + 1];
            double S2 = sums[t * 3 + 2];
            double posw = (nn2 - s) / s;
            double norm = nn2 / ((nn2 - s) * 2.0);
            nll += norm * (-posw * S1 - S2) / nn2;
        }
        out[1] = (float)nll;
    }
}

// ---------------- host ----------------

extern "C" void kernel_launch(void* const* d_in, const int* in_sizes, int n_in,
                              void* d_out, int out_size, void* d_ws, size_t ws_size,
                              hipStream_t stream) {
    (void)in_sizes; (void)n_in; (void)out_size; (void)ws_size;

    const float* x_all = (const float*)d_in[0];
    const int* ei_all = (const int*)d_in[1];
    const float* adj_all = (const float*)d_in[2];
    const float* eps_s_all = (const float*)d_in[3];
    const float* eps_d_all = (const float*)d_in[4];
    const float* phi_x_w = (const float*)d_in[5];
    const float* phi_z_w = (const float*)d_in[6];
    const float* gru_xw0 = (const float*)d_in[7];
    const float* gru_xw1 = (const float*)d_in[8];
    const float* gru_hw = (const float*)d_in[9];
    const float* enc_w = (const float*)d_in[10];
    const float* enc_b = (const float*)d_in[11];
    const float* mean_w = (const float*)d_in[12];
    const float* mean_b = (const float*)d_in[13];
    const float* std_w = (const float*)d_in[14];
    const float* std_b = (const float*)d_in[15];
    const float* pri_w = (const float*)d_in[16];
    const float* pri_b = (const float*)d_in[17];
    const float* pri_mw = (const float*)d_in[18];
    const float* pri_mb = (const float*)d_in[19];
    const float* pri_sw = (const float*)d_in[20];
    const float* pri_sb = (const float*)d_in[21];
    float* out = (float*)d_out;

    size_t off = 0;
    auto alloc = [&](size_t bytes) -> void* {
        void* p = (char*)d_ws + off;
        off = (off + bytes + 255) & ~(size_t)255;
        return p;
    };

    u16* warena = (u16*)alloc(2850816 * 2);
    u16* xb = (u16*)alloc(2 * XSZ * 2);
    u16* phixb = (u16*)alloc((size_t)NTS * 2 * NH * 2);
    u16* hbuf = (u16*)alloc(8 * NH * 2);
    u16* Ub = (u16*)alloc(4 * NH * 2);
    float* prif = (float*)alloc(2 * NH * 4);
    float* xw = (float*)alloc(4 * NZ * 4);
    float* pmps = (float*)alloc(4 * NZ * 4);
    float* zcatf = (float*)alloc(ZPL * 4);
    u16* phizb = (u16*)alloc(2 * NH * 2);
    u16* Pb = (u16*)alloc(6 * NH * 2);
    float* zGf = (float*)alloc(NH * 4);
    u16* Rb = (u16*)alloc(2 * NH * 2);
    float* deg = (float*)alloc((size_t)NTS * NND * 4);
    float* dinv = (float*)alloc((size_t)NTS * NND * 4);
    int* counts = (int*)alloc(2 * (size_t)NTS * NND * 4);
    int* cursor = counts + (size_t)NTS * NND;
    int* offs = (int*)alloc((size_t)NTS * (NND + 1) * 4);
    int* csrc = (int*)alloc((size_t)NTS * NED * 4);
    float* csrw = (float*)alloc((size_t)NTS * NED * 4);
    double* accd = (double*)alloc(8 * 8);
    double* bce = (double*)alloc((size_t)NTS * 1024 * 3 * 8);

    u16* h0b[2] = {hbuf, hbuf + 2 * NH};
    u16* h1b[2] = {hbuf + 4 * NH, hbuf + 6 * NH};

    hipMemsetAsync(hbuf, 0, 8 * NH * 2, stream);
    hipMemsetAsync(counts, 0, 2 * (size_t)NTS * NND * 4, stream);
    hipMemsetAsync(accd, 0, 8 * 8, stream);

    k0_setup<<<10496, 256, 0, stream>>>(ei_all, x_all, phi_x_w, phi_z_w, enc_w, pri_w,
                                        gru_xw0, gru_xw1, gru_hw, warena, xb, counts);
    k1_scan_phix<<<12 + 1536, 256, 0, stream>>>(counts, offs, deg, dinv, xb, warena, phixb);
    k2_fill<<<1536, 256, 0, stream>>>(ei_all, offs, cursor, dinv, csrc, csrw);

    for (int t = 0; t < NTS; ++t) {
        const int cur = t & 1;
        const int* off_t = offs + (size_t)t * (NND + 1);
        const int* cs_t = csrc + (size_t)t * NED;
        const float* cw_t = csrw + (size_t)t * NED;
        const float* dg_t = deg + (size_t)t * NND;
        const u16* phxt = phixb + (size_t)t * 2 * NH;
        const float* adj_t = adj_all + (size_t)t * NND * NND;
        float* dec_t = out + 2 + (size_t)t * NND * NND;
        const float* es_t = eps_s_all + (size_t)t * NZ;
        const float* ed_t = eps_d_all + (size_t)t * NZ;
        double* bce_t = bce + (size_t)t * 1024 * 3;

        kA<<<512, 256, 0, stream>>>(phxt, h1b[cur], warena, Ub, prif, pri_b);
        kB<<<2048, 256, 0, stream>>>(Ub, prif, off_t, cs_t, enc_b, mean_w, std_w,
                                     pri_mw, pri_mb, pri_sw, pri_sb, xw, pmps);
        kC<<<512, 256, 0, stream>>>(xw, pmps, off_t, cs_t, cw_t, dg_t, mean_b, std_b,
                                    es_t, ed_t, phi_z_w, zcatf, phizb, accd);
        kE<<<384 + DECF, 256, 0, stream>>>(phxt, phizb, h0b[cur], warena, Pb,
                                           zcatf, adj_t, dec_t, bce_t, 384, 0);
        kFG<<<128 + DECF, 256, 0, stream>>>(Pb, h0b[cur], warena, 16, zGf, Rb, off_t,
                                            cs_t, zcatf, adj_t, dec_t, bce_t, 128, DECF);
        kH<<<512 + DECF, 256, 0, stream>>>(Rb, zGf, h0b[cur], h0b[cur ^ 1], off_t, cs_t,
                                           zcatf, adj_t, dec_t, bce_t, 512, 2 * DECF, DECF);
        kE1<<<384 + DECF, 256, 0, stream>>>(h0b[cur ^ 1], h1b[cur], warena, Pb,
                                            zcatf, adj_t, dec_t, bce_t, 384, 3 * DECF);
        kFG<<<128 + DECF, 256, 0, stream>>>(Pb, h1b[cur], warena, 22, zGf, Rb, off_t,
                                            cs_t, zcatf, adj_t, dec_t, bce_t, 128, 4 * DECF);
        kH<<<512 + (1024 - 5 * DECF), 256, 0, stream>>>(Rb, zGf, h1b[cur], h1b[cur ^ 1],
                                                        off_t, cs_t, zcatf, adj_t, dec_t,
                                                        bce_t, 512, 5 * DECF,
                                                        1024 - 5 * DECF);
    }

    kFin<<<1, 256, 0, stream>>>(accd, bce, out);
}

// Round 14
// 3030.618 us; speedup vs baseline: 1.1222x; 1.1222x over previous
//
#include <hip/hip_runtime.h>
#include <math.h>

#define NTS 12
#define NND 2048
#define NED 32768
#define XDI 128
#define HDI 256
#define ZDI 32
#define EPSC 1e-10f
#define NH ((size_t)NND * HDI)        // 524288
#define NZ ((size_t)NND * ZDI)        // 65536
#define ZPL ((size_t)NND * 64)        // 131072
#define XSZ ((size_t)NTS * NND * XDI) // 3145728

typedef unsigned short u16;
typedef __bf16 bf16x8 __attribute__((ext_vector_type(8)));
typedef float f32x4 __attribute__((ext_vector_type(4)));

#define MF(a, b, c) __builtin_amdgcn_mfma_f32_16x16x32_bf16(a, b, c, 0, 0, 0)

// ---------------- helpers ----------------

__device__ __forceinline__ float lsigf(float x) {
    return fminf(x, 0.f) - log1pf(expf(-fabsf(x)));
}
__device__ __forceinline__ float splus(float v) {
    return fmaxf(v, 0.f) + log1pf(expf(-fabsf(v)));
}
__device__ __forceinline__ u16 f2b(float f) {
    unsigned u = __float_as_uint(f);
    u += 0x7fffu + ((u >> 16) & 1u);
    return (u16)(u >> 16);
}
__device__ __forceinline__ float b2f(u16 b) {
    return __uint_as_float((unsigned)b << 16);
}
__device__ __forceinline__ void f2b2(float v, u16& hi, u16& lo) {
    hi = f2b(v);
    lo = f2b(v - b2f(hi));
}
__device__ __forceinline__ void st_b16(u16* buf, size_t plane, size_t idx, float v) {
    u16 hi, lo;
    f2b2(v, hi, lo);
    buf[idx] = hi;
    buf[plane + idx] = lo;
}
__device__ __forceinline__ void st_b16v4(u16* buf, size_t plane, size_t idx, float4 v) {
    ushort4 h, l;
    f2b2(v.x, h.x, l.x); f2b2(v.y, h.y, l.y);
    f2b2(v.z, h.z, l.z); f2b2(v.w, h.w, l.w);
    *(ushort4*)(buf + idx) = h;
    *(ushort4*)(buf + plane + idx) = l;
}
__device__ __forceinline__ float4 ld_hl4(const u16* b, size_t plane, size_t idx) {
    ushort4 h = *(const ushort4*)(b + idx);
    ushort4 l = *(const ushort4*)(b + plane + idx);
    float4 r;
    r.x = b2f(h.x) + b2f(l.x); r.y = b2f(h.y) + b2f(l.y);
    r.z = b2f(h.z) + b2f(l.z); r.w = b2f(h.w) + b2f(l.w);
    return r;
}
// gather (GIN) of one 256-wide hi/lo row set — 4-way unrolled (independent chains)
__device__ float4 gin_hl(const u16* buf, size_t plane, int n, const int* __restrict__ offs,
                         const int* __restrict__ cs, int lane) {
    int e0 = offs[n], e1 = offs[n + 1];
    size_t c4 = (size_t)lane * 4;
    float4 a0 = ld_hl4(buf, plane, (size_t)n * HDI + c4);
    float4 a1 = {0.f, 0.f, 0.f, 0.f}, a2 = {0.f, 0.f, 0.f, 0.f}, a3 = {0.f, 0.f, 0.f, 0.f};
    int j = e0;
    for (; j + 3 < e1; j += 4) {
        int s0 = cs[j], s1 = cs[j + 1], s2 = cs[j + 2], s3 = cs[j + 3];
        float4 v0 = ld_hl4(buf, plane, (size_t)s0 * HDI + c4);
        float4 v1 = ld_hl4(buf, plane, (size_t)s1 * HDI + c4);
        float4 v2 = ld_hl4(buf, plane, (size_t)s2 * HDI + c4);
        float4 v3 = ld_hl4(buf, plane, (size_t)s3 * HDI + c4);
        a0.x += v0.x; a0.y += v0.y; a0.z += v0.z; a0.w += v0.w;
        a1.x += v1.x; a1.y += v1.y; a1.z += v1.z; a1.w += v1.w;
        a2.x += v2.x; a2.y += v2.y; a2.z += v2.z; a2.w += v2.w;
        a3.x += v3.x; a3.y += v3.y; a3.z += v3.z; a3.w += v3.w;
    }
    for (; j < e1; ++j) {
        float4 v = ld_hl4(buf, plane, (size_t)cs[j] * HDI + c4);
        a0.x += v.x; a0.y += v.y; a0.z += v.z; a0.w += v.w;
    }
    a0.x += a1.x + a2.x + a3.x;
    a0.y += a1.y + a2.y + a3.y;
    a0.z += a1.z + a2.z + a3.z;
    a0.w += a1.w + a2.w + a3.w;
    return a0;
}

// wt arena offsets (elems): m0 K=128, m1 K=64, else K=256; each = 2*K*256 elems
__host__ __device__ inline size_t wtoff(int m) {
    if (m == 0) return 0;
    if (m == 1) return 65536;
    return 98304 + (size_t)(m - 2) * 131072;
}

// split-bf16 64x16 wave GEMM pass: 12 accumulators (4 row-subtiles x 3-split)
__device__ __forceinline__ void mm64(f32x4* A12, const u16* __restrict__ Ahi, size_t apl,
                                     const u16* __restrict__ Bt, int K,
                                     int row0, int cc, int lr, int kg) {
    const u16* bp = Bt + (size_t)(cc * 16 + lr) * K + kg;
    const u16* blp = bp + (size_t)K * HDI;
    const u16* ap0 = Ahi + (size_t)(row0 + lr) * K + kg;
    for (int k0 = 0; k0 < K; k0 += 32) {
        bf16x8 bh = *(const bf16x8*)(bp + k0);
        bf16x8 bl = *(const bf16x8*)(blp + k0);
#pragma unroll
        for (int s = 0; s < 4; s++) {
            const u16* ap = ap0 + (size_t)(16 * s) * K;
            bf16x8 ah = *(const bf16x8*)(ap + k0);
            bf16x8 al = *(const bf16x8*)(ap + apl + k0);
            A12[s * 3 + 0] = MF(ah, bh, A12[s * 3 + 0]);
            A12[s * 3 + 1] = MF(al, bh, A12[s * 3 + 1]);
            A12[s * 3 + 2] = MF(ah, bl, A12[s * 3 + 2]);
        }
    }
}

__device__ __forceinline__ void epi_hl(f32x4* A12, u16* dst, size_t plane,
                                       int row0, int cc, int lane, int relu) {
    int col = cc * 16 + (lane & 15);
    int rb0 = (lane >> 4) << 2;
#pragma unroll
    for (int s = 0; s < 4; s++)
#pragma unroll
        for (int i = 0; i < 4; i++) {
            int row = row0 + s * 16 + rb0 + i;
            float v = A12[s * 3][i] + A12[s * 3 + 1][i] + A12[s * 3 + 2][i];
            if (relu) v = fmaxf(v, 0.f);
            st_b16(dst, plane, (size_t)row * HDI + col, v);
        }
}

// ---------------- setup kernels ----------------

__global__ __launch_bounds__(256) void k0_setup(const int* __restrict__ ei,
                                                const float* __restrict__ x,
                                                const float* w_phix, const float* w_phiz,
                                                const float* w_enc, const float* w_pri,
                                                const float* w_gx0, const float* w_gx1,
                                                const float* w_gh,
                                                u16* __restrict__ warena, u16* __restrict__ xb,
                                                int* __restrict__ counts) {
    const int bid = blockIdx.x, tid = threadIdx.x;
    if (bid < 1536) {
        int idx = bid * 256 + tid;
        int t = idx >> 15, e = idx & (NED - 1);
        atomicAdd(&counts[t * NND + ei[(size_t)t * 2 * NED + NED + e]], 1);
    } else if (bid < 7424) {
        int u = bid - 1536;
        int m = u >> 8, k = u & 255;
        const int Kt = (m == 0) ? 128 : (m == 1) ? 64 : 256;
        if (k < Kt) {
            const int srcsel[23] = {0, 1, 2, 2, 2, 2, 3, 3, 4, 4, 4, 4,
                                    4, 4, 6, 6, 6, 5, 5, 5, 6, 6, 6};
            const int srcoff[23] = {0, 0, 0, 65536, 131072, 196608, 0, 65536,
                                    0, 65536, 131072, 196608, 262144, 327680,
                                    0, 65536, 131072, 0, 65536, 131072,
                                    196608, 262144, 327680};
            const float* srcs[7] = {w_phix, w_phiz, w_enc, w_pri, w_gx0, w_gx1, w_gh};
            const float* W = srcs[srcsel[m]] + srcoff[m];
            u16* D = warena + wtoff(m);
            float v = W[(size_t)k * 256 + tid];
            u16 hi, lo;
            f2b2(v, hi, lo);
            D[(size_t)tid * Kt + k] = hi;
            D[(size_t)Kt * 256 + (size_t)tid * Kt + k] = lo;
        }
    } else {
        size_t i = (size_t)(bid - 7424) * 256 + tid;
        float4 v = ((const float4*)x)[i];
        ushort4 h, l;
        f2b2(v.x, h.x, l.x); f2b2(v.y, h.y, l.y);
        f2b2(v.z, h.z, l.z); f2b2(v.w, h.w, l.w);
        ((ushort4*)xb)[i] = h;
        ((ushort4*)(xb + XSZ))[i] = l;
    }
}

// k1: per-t scan (blocks 0..11) + all-t phi_x GEMM (relu, hi/lo out)
__global__ __launch_bounds__(256) void k1_scan_phix(const int* __restrict__ counts,
                                                    int* __restrict__ offs,
                                                    float* __restrict__ deg,
                                                    float* __restrict__ dinv,
                                                    const u16* __restrict__ xb,
                                                    const u16* __restrict__ warena,
                                                    u16* __restrict__ phixb) {
    __shared__ int tsum[256];
    const int bid = blockIdx.x, tid = threadIdx.x;
    if (bid < 12) {
        const int* cnt = counts + bid * NND;
        int* off = offs + bid * (NND + 1);
        float* dg = deg + bid * NND;
        float* dv = dinv + bid * NND;
        int base = tid * 8;
        int local[8];
        int s = 0;
        for (int i = 0; i < 8; i++) { local[i] = s; s += cnt[base + i]; }
        tsum[tid] = s;
        __syncthreads();
        for (int o = 1; o < 256; o <<= 1) {
            int v = (tid >= o) ? tsum[tid - o] : 0;
            __syncthreads();
            tsum[tid] += v;
            __syncthreads();
        }
        int excl = tsum[tid] - s;
        for (int i = 0; i < 8; i++) off[base + i] = excl + local[i];
        if (tid == 255) off[NND] = excl + s;
        for (int i = 0; i < 8; i++) {
            float d = (float)cnt[base + i] + 1.0f;
            dg[base + i] = d;
            dv[base + i] = 1.0f / sqrtf(d);
        }
    } else {
        int u = bid - 12;
        int t = u >> 7, tile = u & 127;
        const int wid = tid >> 6, lane = tid & 63;
        const int lr = lane & 15, kg = (lane >> 4) * 8;
        int row0 = (tile >> 4) * 256 + wid * 64, cc = tile & 15;
        f32x4 A12[12] = {};
        mm64(A12, xb + (size_t)t * NND * XDI, XSZ, warena + wtoff(0), XDI, row0, cc, lr, kg);
        epi_hl(A12, phixb + (size_t)t * 2 * NH, NH, row0, cc, lane, 1);
    }
}

// k2: CSR fill
__global__ __launch_bounds__(256) void k2_fill(const int* __restrict__ ei,
                                               const int* __restrict__ offs,
                                               int* __restrict__ cursor,
                                               const float* __restrict__ dinv,
                                               int* __restrict__ csrc,
                                               float* __restrict__ csrw) {
    int idx = blockIdx.x * 256 + threadIdx.x;
    int t = idx >> 15, e = idx & (NED - 1);
    const int* src = ei + (size_t)t * 2 * NED;
    const int* dst = src + NED;
    int d = dst[e], s = src[e];
    const int* off_t = offs + t * (NND + 1);
    int pos = off_t[d] + atomicAdd(&cursor[t * NND + d], 1);
    csrc[(size_t)t * NED + pos] = s;
    csrw[(size_t)t * NED + pos] = dinv[t * NND + s] * dinv[t * NND + d];
}

// ---------------- per-step kernels ----------------

// kA: U_s/U_d GEMM (hi/lo out) + pri GEMM (fp32 relu out)
__global__ __launch_bounds__(256) void kA(const u16* __restrict__ phxt,
                                          const u16* __restrict__ h1b,
                                          const u16* __restrict__ warena,
                                          u16* __restrict__ Ub, float* __restrict__ prif,
                                          const float* __restrict__ b_pri) {
    const int bid = blockIdx.x, tid = threadIdx.x;
    const int wid = tid >> 6, lane = tid & 63;
    const int lr = lane & 15, kg = (lane >> 4) * 8;
    f32x4 A12[12] = {};
    if (bid < 256) {
        int o = bid >> 7, tile = bid & 127;
        int row0 = (tile >> 4) * 256 + wid * 64, cc = tile & 15;
        mm64(A12, phxt, NH, warena + wtoff(2 + 2 * o), HDI, row0, cc, lr, kg);
        mm64(A12, h1b, NH, warena + wtoff(3 + 2 * o), HDI, row0, cc, lr, kg);
        epi_hl(A12, Ub + (size_t)o * 2 * NH, NH, row0, cc, lane, 0);
    } else {
        int q = bid - 256;
        int o = q >> 7, tile = q & 127;
        int row0 = (tile >> 4) * 256 + wid * 64, cc = tile & 15;
        mm64(A12, h1b, NH, warena + wtoff(6 + o), HDI, row0, cc, lr, kg);
        int col = cc * 16 + lr;
        int rb0 = (lane >> 4) << 2;
        float* C = prif + (size_t)o * NH;
        float bv = b_pri[o * HDI + col];
#pragma unroll
        for (int s = 0; s < 4; s++)
#pragma unroll
            for (int i = 0; i < 4; i++) {
                int row = row0 + s * 16 + rb0 + i;
                float v = A12[s * 3][i] + A12[s * 3 + 1][i] + A12[s * 3 + 2][i] + bv;
                C[(size_t)row * HDI + col] = fmaxf(v, 0.f);
            }
    }
}

// kB: fused enc gather + [256->32] smalls, plus prior smalls
__global__ __launch_bounds__(256) void kB(const u16* __restrict__ Ub,
                                          const float* __restrict__ prif,
                                          const int* __restrict__ offs,
                                          const int* __restrict__ cs,
                                          const float* __restrict__ b_enc,
                                          const float* __restrict__ w_mean,
                                          const float* __restrict__ w_std,
                                          const float* __restrict__ w_pm,
                                          const float* __restrict__ b_pm,
                                          const float* __restrict__ w_ps,
                                          const float* __restrict__ b_ps,
                                          float* __restrict__ xw, float* __restrict__ pmps) {
    __shared__ float rowbuf[4][256];
    const int tid = threadIdx.x;
    const int wid = tid >> 6, lane = tid & 63;
    const int u = blockIdx.x * 4 + wid;
    if (u < 4096) {
        int seg = u >> 11, n = u & 2047;
        float4 a = gin_hl(Ub + (size_t)seg * 2 * NH, NH, n, offs, cs, lane);
        const float* eb = b_enc + seg * HDI + lane * 4;
        a.x = fmaxf(a.x + eb[0], 0.f);
        a.y = fmaxf(a.y + eb[1], 0.f);
        a.z = fmaxf(a.z + eb[2], 0.f);
        a.w = fmaxf(a.w + eb[3], 0.f);
        *(float4*)&rowbuf[wid][lane * 4] = a;
        const float* B = ((lane < 32) ? w_mean : w_std) + seg * 8192;
        int m = lane & 31;
        float acc = 0.f;
        const float* rb = rowbuf[wid];
#pragma unroll 8
        for (int k = 0; k < 256; k++) acc += rb[k] * B[k * 32 + m];
        float* O = xw + ((lane < 32) ? seg : 2 + seg) * NZ;
        O[(size_t)n * ZDI + m] = acc;
    } else {
        int q = u - 4096;
        int s = q >> 10, unit = q & 1023;
        int n = unit * 2 + (lane >> 5);
        int m = lane & 31;
        const float* A = prif + ((s < 2) ? 0 : NH);
        const float* B = (s & 1) ? (w_ps + (s >> 1) * 8192) : (w_pm + (s >> 1) * 8192);
        const float* bi = (s & 1) ? (b_ps + (s >> 1) * 32) : (b_pm + (s >> 1) * 32);
        float acc = bi[m];
        const float* ar = A + (size_t)n * HDI;
#pragma unroll 4
        for (int k = 0; k < 256; k += 4) {
            float4 a4 = *(const float4*)(ar + k);
            acc += a4.x * B[(k + 0) * 32 + m];
            acc += a4.y * B[(k + 1) * 32 + m];
            acc += a4.z * B[(k + 2) * 32 + m];
            acc += a4.w * B[(k + 3) * 32 + m];
        }
        if (s & 1) acc = splus(acc);
        pmps[(size_t)s * NZ + (size_t)n * ZDI + m] = acc;
    }
}

// kC: fused gcn(mean)+gin(std)+z+KLD — 4-way unrolled gathers
__global__ __launch_bounds__(256) void kC(const float* __restrict__ xw,
                                          const float* __restrict__ pmps,
                                          const int* __restrict__ offs,
                                          const int* __restrict__ cs,
                                          const float* __restrict__ cw,
                                          const float* __restrict__ dgv,
                                          const float* __restrict__ b_mean,
                                          const float* __restrict__ b_std,
                                          const float* __restrict__ es,
                                          const float* __restrict__ ed,
                                          float* __restrict__ zcatf, u16* __restrict__ zcatb,
                                          double* __restrict__ accd) {
    __shared__ double smd[4];
    const int tid = threadIdx.x;
    const int wid = tid >> 6, lane = tid & 63;
    const int n = blockIdx.x * 4 + wid;
    const int sel = lane >> 5, m = lane & 31;
    const float* xwm = xw + (size_t)sel * NZ;
    const float* xws = xw + (size_t)(2 + sel) * NZ;
    int e0 = offs[n], e1 = offs[n + 1];
    float am0 = 0.f, am1 = 0.f, am2 = 0.f, am3 = 0.f;
    float as0 = xws[(size_t)n * ZDI + m], as1 = 0.f, as2 = 0.f, as3 = 0.f;
    int j = e0;
    for (; j + 3 < e1; j += 4) {
        int s0 = cs[j], s1 = cs[j + 1], s2 = cs[j + 2], s3 = cs[j + 3];
        am0 += cw[j] * xwm[(size_t)s0 * ZDI + m];
        am1 += cw[j + 1] * xwm[(size_t)s1 * ZDI + m];
        am2 += cw[j + 2] * xwm[(size_t)s2 * ZDI + m];
        am3 += cw[j + 3] * xwm[(size_t)s3 * ZDI + m];
        as0 += xws[(size_t)s0 * ZDI + m];
        as1 += xws[(size_t)s1 * ZDI + m];
        as2 += xws[(size_t)s2 * ZDI + m];
        as3 += xws[(size_t)s3 * ZDI + m];
    }
    for (; j < e1; ++j) {
        int s = cs[j];
        am0 += cw[j] * xwm[(size_t)s * ZDI + m];
        as0 += xws[(size_t)s * ZDI + m];
    }
    float am = am0 + am1 + am2 + am3;
    float as_ = as0 + as1 + as2 + as3;
    float mean = am + xwm[(size_t)n * ZDI + m] / dgv[n] + b_mean[sel * 32 + m];
    float sd = splus(as_ + b_std[sel * 32 + m]);
    const float* eps = sel ? ed : es;
    float z = mean + sd * eps[(size_t)n * ZDI + m];
    size_t zi = (size_t)n * 64 + sel * 32 + m;
    zcatf[zi] = z;
    st_b16(zcatb, ZPL, zi, z);
    float pm = pmps[(size_t)(sel * 2) * NZ + (size_t)n * ZDI + m];
    float ps = pmps[(size_t)(sel * 2 + 1) * NZ + (size_t)n * ZDI + m];
    float a1v = sd + EPSC, a2v = ps + EPSC;
    float dm = mean - pm;
    double kl = (double)(2.f * (logf(a2v) - logf(a1v)) +
                         (a1v * a1v + dm * dm) / (a2v * a2v) - 1.f);
#pragma unroll
    for (int o = 32; o > 0; o >>= 1) kl += __shfl_down(kl, o);
    if (lane == 0) smd[wid] = kl;
    __syncthreads();
    if (tid == 0) atomicAdd(accd, smd[0] + smd[1] + smd[2] + smd[3]);
}

// kD: dec + BCE partials (blocks 0..1023) || phi_z GEMM (blocks 1024..1151)
__global__ __launch_bounds__(256) void kD(const float* __restrict__ zcatf,
                                          const u16* __restrict__ zcatb,
                                          const float* __restrict__ adjt,
                                          const u16* __restrict__ warena,
                                          float* __restrict__ dect,
                                          u16* __restrict__ phizb,
                                          double* __restrict__ bcet) {
    __shared__ float smf[2 * 32 * 68];
    const int bid = blockIdx.x, tid = threadIdx.x;
    if (bid < 1024) {
        float (*zsS)[68] = (float(*)[68])smf;
        float (*zdS)[68] = (float(*)[68])(smf + 32 * 68);
        const int tx = tid & 15, ty = tid >> 4;
        const int c0 = (bid & 31) * 64, r0 = (bid >> 5) * 64;
        const int lrow = tid >> 2;
        const int lk = (tid & 3) * 8;
        float4 v0 = *(const float4*)&zcatf[(size_t)(r0 + lrow) * 64 + lk];
        float4 v1 = *(const float4*)&zcatf[(size_t)(r0 + lrow) * 64 + lk + 4];
        float4 w0 = *(const float4*)&zcatf[(size_t)(c0 + lrow) * 64 + 32 + lk];
        float4 w1 = *(const float4*)&zcatf[(size_t)(c0 + lrow) * 64 + 32 + lk + 4];
        zsS[lk + 0][lrow] = v0.x; zsS[lk + 1][lrow] = v0.y; zsS[lk + 2][lrow] = v0.z; zsS[lk + 3][lrow] = v0.w;
        zsS[lk + 4][lrow] = v1.x; zsS[lk + 5][lrow] = v1.y; zsS[lk + 6][lrow] = v1.z; zsS[lk + 7][lrow] = v1.w;
        zdS[lk + 0][lrow] = w0.x; zdS[lk + 1][lrow] = w0.y; zdS[lk + 2][lrow] = w0.z; zdS[lk + 3][lrow] = w0.w;
        zdS[lk + 4][lrow] = w1.x; zdS[lk + 5][lrow] = w1.y; zdS[lk + 6][lrow] = w1.z; zdS[lk + 7][lrow] = w1.w;
        __syncthreads();

        float acc[4][4] = {};
#pragma unroll
        for (int k = 0; k < 32; k++) {
            const float4 a4 = *(const float4*)&zsS[k][ty * 4];
            const float4 b4 = *(const float4*)&zdS[k][tx * 4];
            const float aa[4] = {a4.x, a4.y, a4.z, a4.w};
            const float bb[4] = {b4.x, b4.y, b4.z, b4.w};
#pragma unroll
            for (int i = 0; i < 4; i++)
#pragma unroll
                for (int j = 0; j < 4; j++) acc[i][j] += aa[i] * bb[j];
        }

        float pa = 0.f, p1 = 0.f, p2 = 0.f;
#pragma unroll
        for (int i = 0; i < 4; i++) {
            const int r = r0 + ty * 4 + i;
            const float4 av4 = *(const float4*)&adjt[(size_t)r * NND + c0 + tx * 4];
            const float av[4] = {av4.x, av4.y, av4.z, av4.w};
            float* drow = &dect[(size_t)r * NND + c0 + tx * 4];
#pragma unroll
            for (int j = 0; j < 4; j++) {
                float d = acc[i][j];
                __builtin_nontemporal_store(d, &drow[j]);
                float a = av[j];
                pa += a;
                p1 += a * lsigf(d);
                p2 += (1.f - a) * lsigf(-d);
            }
        }
        __syncthreads();
        smf[tid] = pa; smf[256 + tid] = p1; smf[512 + tid] = p2;
        __syncthreads();
        for (int o = 128; o > 0; o >>= 1) {
            if (tid < o) {
                smf[tid] += smf[tid + o];
                smf[256 + tid] += smf[256 + tid + o];
                smf[512 + tid] += smf[512 + tid + o];
            }
            __syncthreads();
        }
        if (tid == 0) {
            double* b = bcet + (size_t)bid * 3;
            b[0] = (double)smf[0];
            b[1] = (double)smf[256];
            b[2] = (double)smf[512];
        }
    } else {
        int u = bid - 1024;
        const int wid = tid >> 6, lane = tid & 63;
        const int lr = lane & 15, kg = (lane >> 4) * 8;
        int row0 = (u >> 4) * 256 + wid * 64, cc = u & 15;
        f32x4 A12[12] = {};
        mm64(A12, zcatb, ZPL, warena + wtoff(1), 64, row0, cc, lr, kg);
        epi_hl(A12, phizb, NH, row0, cc, lane, 1);
    }
}

// kE: GRU layer0 gate GEMMs (Pz,Pr,Ph), hi/lo out
__global__ __launch_bounds__(256) void kE(const u16* __restrict__ phxt,
                                          const u16* __restrict__ phizb,
                                          const u16* __restrict__ h0b,
                                          const u16* __restrict__ warena,
                                          u16* __restrict__ Pb) {
    const int bid = blockIdx.x, tid = threadIdx.x;
    const int wid = tid >> 6, lane = tid & 63;
    const int lr = lane & 15, kg = (lane >> 4) * 8;
    int o = bid >> 7, tile = bid & 127;
    int row0 = (tile >> 4) * 256 + wid * 64, cc = tile & 15;
    f32x4 A12[12] = {};
    if (o == 0) {
        mm64(A12, phxt, NH, warena + wtoff(8), HDI, row0, cc, lr, kg);
        mm64(A12, phizb, NH, warena + wtoff(9), HDI, row0, cc, lr, kg);
        mm64(A12, h0b, NH, warena + wtoff(14), HDI, row0, cc, lr, kg);
    } else if (o == 1) {
        mm64(A12, phxt, NH, warena + wtoff(10), HDI, row0, cc, lr, kg);
        mm64(A12, phizb, NH, warena + wtoff(11), HDI, row0, cc, lr, kg);
        mm64(A12, h0b, NH, warena + wtoff(15), HDI, row0, cc, lr, kg);
    } else {
        mm64(A12, phxt, NH, warena + wtoff(12), HDI, row0, cc, lr, kg);
        mm64(A12, phizb, NH, warena + wtoff(13), HDI, row0, cc, lr, kg);
    }
    epi_hl(A12, Pb + (size_t)o * 2 * NH, NH, row0, cc, lane, 0);
}

// kE1: GRU layer1 gate GEMMs
__global__ __launch_bounds__(256) void kE1(const u16* __restrict__ nh0b,
                                           const u16* __restrict__ h1b,
                                           const u16* __restrict__ warena,
                                           u16* __restrict__ Pb) {
    const int bid = blockIdx.x, tid = threadIdx.x;
    const int wid = tid >> 6, lane = tid & 63;
    const int lr = lane & 15, kg = (lane >> 4) * 8;
    int o = bid >> 7, tile = bid & 127;
    int row0 = (tile >> 4) * 256 + wid * 64, cc = tile & 15;
    f32x4 A12[12] = {};
    if (o == 0) {
        mm64(A12, nh0b, NH, warena + wtoff(17), HDI, row0, cc, lr, kg);
        mm64(A12, h1b, NH, warena + wtoff(20), HDI, row0, cc, lr, kg);
    } else if (o == 1) {
        mm64(A12, nh0b, NH, warena + wtoff(18), HDI, row0, cc, lr, kg);
        mm64(A12, h1b, NH, warena + wtoff(21), HDI, row0, cc, lr, kg);
    } else {
        mm64(A12, nh0b, NH, warena + wtoff(19), HDI, row0, cc, lr, kg);
    }
    epi_hl(A12, Pb + (size_t)o * 2 * NH, NH, row0, cc, lane, 0);
}

// kF: zG = sig(G(Pz)) fp32; rh = sig(G(Pr))*h (hi/lo)
__global__ __launch_bounds__(256) void kF(const u16* __restrict__ Pb,
                                          const u16* __restrict__ hb,
                                          float* __restrict__ zGf, u16* __restrict__ rhb,
                                          const int* __restrict__ offs,
                                          const int* __restrict__ cs) {
    const int tid = threadIdx.x;
    const int wid = tid >> 6, lane = tid & 63;
    const int u = blockIdx.x * 4 + wid;
    int seg = u >> 11, n = u & 2047;
    size_t idx = (size_t)n * HDI + lane * 4;
    if (seg == 0) {
        float4 a = gin_hl(Pb, NH, n, offs, cs, lane);
        a.x = 1.f / (1.f + expf(-a.x)); a.y = 1.f / (1.f + expf(-a.y));
        a.z = 1.f / (1.f + expf(-a.z)); a.w = 1.f / (1.f + expf(-a.w));
        *(float4*)&zGf[idx] = a;
    } else {
        float4 a = gin_hl(Pb + 2 * NH, NH, n, offs, cs, lane);
        float4 h4 = ld_hl4(hb, NH, idx);
        float4 rh;
        rh.x = h4.x / (1.f + expf(-a.x)); rh.y = h4.y / (1.f + expf(-a.y));
        rh.z = h4.z / (1.f + expf(-a.z)); rh.w = h4.w / (1.f + expf(-a.w));
        st_b16v4(rhb, NH, idx, rh);
    }
}

// kG: R = rh@Whh + Ph (hi/lo out); wtm selects weight (16 or 22)
__global__ __launch_bounds__(256) void kG(const u16* __restrict__ rhb,
                                          const u16* __restrict__ warena, int wtm,
                                          const u16* __restrict__ Pb, u16* __restrict__ Rb) {
    const int bid = blockIdx.x, tid = threadIdx.x;
    const int wid = tid >> 6, lane = tid & 63;
    const int lr = lane & 15, kg = (lane >> 4) * 8;
    int row0 = (bid >> 4) * 256 + wid * 64, cc = bid & 15;
    f32x4 A12[12] = {};
    mm64(A12, rhb, NH, warena + wtoff(wtm), HDI, row0, cc, lr, kg);
    const u16* Ph = Pb + 4 * NH;
    int col = cc * 16 + lr;
    int rb0 = (lane >> 4) << 2;
#pragma unroll
    for (int s = 0; s < 4; s++)
#pragma unroll
        for (int i = 0; i < 4; i++) {
            int row = row0 + s * 16 + rb0 + i;
            size_t idx = (size_t)row * HDI + col;
            float v = A12[s * 3][i] + A12[s * 3 + 1][i] + A12[s * 3 + 2][i] +
                      b2f(Ph[idx]) + b2f(Ph[NH + idx]);
            st_b16(Rb, NH, idx, v);
        }
}

// kH: nh = zG*h + (1-zG)*tanh(G(R)) (hi/lo out)
__global__ __launch_bounds__(256) void kH(const u16* __restrict__ Rb,
                                          const float* __restrict__ zGf,
                                          const u16* __restrict__ hb,
                                          u16* __restrict__ nhb,
                                          const int* __restrict__ offs,
                                          const int* __restrict__ cs) {
    const int tid = threadIdx.x;
    const int wid = tid >> 6, lane = tid & 63;
    const int n = blockIdx.x * 4 + wid;
    size_t idx = (size_t)n * HDI + lane * 4;
    float4 a = gin_hl(Rb, NH, n, offs, cs, lane);
    float4 z4 = *(const float4*)&zGf[idx];
    float4 h4 = ld_hl4(hb, NH, idx);
    float4 o;
    o.x = z4.x * h4.x + (1.f - z4.x) * tanhf(a.x);
    o.y = z4.y * h4.y + (1.f - z4.y) * tanhf(a.y);
    o.z = z4.z * h4.z + (1.f - z4.z) * tanhf(a.z);
    o.w = z4.w * h4.w + (1.f - z4.w) * tanhf(a.w);
    st_b16v4(nhb, NH, idx, o);
}

// finalize — wave-parallel reductions
__global__ __launch_bounds__(256) void kFin(const double* __restrict__ accd,
                                            const double* __restrict__ bce,
                                            float* __restrict__ out) {
    __shared__ double sums[36];
    const int tid = threadIdx.x;
    const int wid = tid >> 6, lane = tid & 63;
    for (int p = wid; p < 36; p += 4) {
        int t = p / 3, c = p % 3;
        double s = 0.0;
        for (int i = lane; i < 1024; i += 64) s += bce[((size_t)t * 1024 + i) * 3 + c];
#pragma unroll
        for (int o = 32; o > 0; o >>= 1) s += __shfl_down(s, o);
        if (lane == 0) sums[p] = s;
    }
    __syncthreads();
    if (tid == 0) {
        const double nn2 = (double)NND * (double)NND;
        out[0] = (float)(0.5 * accd[0] / nn2);
        double nll = 0.0;
        for (int t = 0; t < NTS; ++t) {
            double s = sums[t * 3 + 0];
            double S1 = sums[t * 3 + 1];
            double S2 = sums[t * 3 + 2];
            double posw = (nn2 - s) / s;
            double norm = nn2 / ((nn2 - s) * 2.0);
            nll += norm * (-posw * S1 - S2) / nn2;
        }
        out[1] = (float)nll;
    }
}

// ---------------- host ----------------

extern "C" void kernel_launch(void* const* d_in, const int* in_sizes, int n_in,
                              void* d_out, int out_size, void* d_ws, size_t ws_size,
                              hipStream_t stream) {
    (void)in_sizes; (void)n_in; (void)out_size; (void)ws_size;

    const float* x_all = (const float*)d_in[0];
    const int* ei_all = (const int*)d_in[1];
    const float* adj_all = (const float*)d_in[2];
    const float* eps_s_all = (const float*)d_in[3];
    const float* eps_d_all = (const float*)d_in[4];
    const float* phi_x_w = (const float*)d_in[5];
    const float* phi_z_w = (const float*)d_in[6];
    const float* gru_xw0 = (const float*)d_in[7];
    const float* gru_xw1 = (const float*)d_in[8];
    const float* gru_hw = (const float*)d_in[9];
    const float* enc_w = (const float*)d_in[10];
    const float* enc_b = (const float*)d_in[11];
    const float* mean_w = (const float*)d_in[12];
    const float* mean_b = (const float*)d_in[13];
    const float* std_w = (const float*)d_in[14];
    const float* std_b = (const float*)d_in[15];
    const float* pri_w = (const float*)d_in[16];
    const float* pri_b = (const float*)d_in[17];
    const float* pri_mw = (const float*)d_in[18];
    const float* pri_mb = (const float*)d_in[19];
    const float* pri_sw = (const float*)d_in[20];
    const float* pri_sb = (const float*)d_in[21];
    float* out = (float*)d_out;

    size_t off = 0;
    auto alloc = [&](size_t bytes) -> void* {
        void* p = (char*)d_ws + off;
        off = (off + bytes + 255) & ~(size_t)255;
        return p;
    };

    u16* warena = (u16*)alloc(2850816 * 2);
    u16* xb = (u16*)alloc(2 * XSZ * 2);
    u16* phixb = (u16*)alloc((size_t)NTS * 2 * NH * 2);
    u16* hbuf = (u16*)alloc(8 * NH * 2);
    u16* Ub = (u16*)alloc(4 * NH * 2);
    float* prif = (float*)alloc(2 * NH * 4);
    float* xw = (float*)alloc(4 * NZ * 4);
    float* pmps = (float*)alloc(4 * NZ * 4);
    float* zcatf = (float*)alloc(ZPL * 4);
    u16* zcatb = (u16*)alloc(2 * ZPL * 2);
    u16* phizb = (u16*)alloc(2 * NH * 2);
    u16* Pb = (u16*)alloc(6 * NH * 2);
    float* zGf = (float*)alloc(NH * 4);
    u16* rhb = (u16*)alloc(2 * NH * 2);
    u16* Rb = (u16*)alloc(2 * NH * 2);
    float* deg = (float*)alloc((size_t)NTS * NND * 4);
    float* dinv = (float*)alloc((size_t)NTS * NND * 4);
    int* counts = (int*)alloc(2 * (size_t)NTS * NND * 4);
    int* cursor = counts + (size_t)NTS * NND;
    int* offs = (int*)alloc((size_t)NTS * (NND + 1) * 4);
    int* csrc = (int*)alloc((size_t)NTS * NED * 4);
    float* csrw = (float*)alloc((size_t)NTS * NED * 4);
    double* accd = (double*)alloc(8 * 8);
    double* bce = (double*)alloc((size_t)NTS * 1024 * 3 * 8);

    u16* h0b[2] = {hbuf, hbuf + 2 * NH};
    u16* h1b[2] = {hbuf + 4 * NH, hbuf + 6 * NH};

    hipMemsetAsync(hbuf, 0, 8 * NH * 2, stream);
    hipMemsetAsync(counts, 0, 2 * (size_t)NTS * NND * 4, stream);
    hipMemsetAsync(accd, 0, 8 * 8, stream);

    k0_setup<<<10496, 256, 0, stream>>>(ei_all, x_all, phi_x_w, phi_z_w, enc_w, pri_w,
                                        gru_xw0, gru_xw1, gru_hw, warena, xb, counts);
    k1_scan_phix<<<12 + 1536, 256, 0, stream>>>(counts, offs, deg, dinv, xb, warena, phixb);
    k2_fill<<<1536, 256, 0, stream>>>(ei_all, offs, cursor, dinv, csrc, csrw);

    for (int t = 0; t < NTS; ++t) {
        const int cur = t & 1;
        const int* off_t = offs + (size_t)t * (NND + 1);
        const int* cs_t = csrc + (size_t)t * NED;
        const float* cw_t = csrw + (size_t)t * NED;
        const float* dg_t = deg + (size_t)t * NND;
        const u16* phxt = phixb + (size_t)t * 2 * NH;
        const float* adj_t = adj_all + (size_t)t * NND * NND;
        float* dec_t = out + 2 + (size_t)t * NND * NND;
        const float* es_t = eps_s_all + (size_t)t * NZ;
        const float* ed_t = eps_d_all + (size_t)t * NZ;
        double* bce_t = bce + (size_t)t * 1024 * 3;

        kA<<<512, 256, 0, stream>>>(phxt, h1b[cur], warena, Ub, prif, pri_b);
        kB<<<2048, 256, 0, stream>>>(Ub, prif, off_t, cs_t, enc_b, mean_w, std_w,
                                     pri_mw, pri_mb, pri_sw, pri_sb, xw, pmps);
        kC<<<512, 256, 0, stream>>>(xw, pmps, off_t, cs_t, cw_t, dg_t, mean_b, std_b,
                                    es_t, ed_t, zcatf, zcatb, accd);
        kD<<<1152, 256, 0, stream>>>(zcatf, zcatb, adj_t, warena, dec_t, phizb, bce_t);
        kE<<<384, 256, 0, stream>>>(phxt, phizb, h0b[cur], warena, Pb);
        kF<<<1024, 256, 0, stream>>>(Pb, h0b[cur], zGf, rhb, off_t, cs_t);
        kG<<<128, 256, 0, stream>>>(rhb, warena, 16, Pb, Rb);
        kH<<<512, 256, 0, stream>>>(Rb, zGf, h0b[cur], h0b[cur ^ 1], off_t, cs_t);
        kE1<<<384, 256, 0, stream>>>(h0b[cur ^ 1], h1b[cur], warena, Pb);
        kF<<<1024, 256, 0, stream>>>(Pb, h1b[cur], zGf, rhb, off_t, cs_t);
        kG<<<128, 256, 0, stream>>>(rhb, warena, 22, Pb, Rb);
        kH<<<512, 256, 0, stream>>>(Rb, zGf, h1b[cur], h1b[cur ^ 1], off_t, cs_t);
    }

    kFin<<<1, 256, 0, stream>>>(accd, bce, out);
}